// Round 2
// baseline (272.231 us; speedup 1.0000x reference)
//
#include <hip/hip_runtime.h>

// B=16, C=64, H=W=192, K=3 (fixed).
// Kernel 1: ker[b,c,i,j] from the tiny MLP (16 blocks, writes 9216 floats to ws).
// Kernel 2 (v5): depthwise 3x3 via LDS tile staging.
//   - Block = one (b,c) plane x 32 output rows. Stages 34 rows (32+2 halo,
//     26112 B, padded to 7*4096) into LDS with global_load_lds width=16:
//     loads are fire-and-forget into the vmcnt queue -> in-flight bytes no
//     longer limited by VGPRs (v3/v4 were latency-bound at ~2.5 TB/s).
//   - Compute: each thread owns 3 tasks of (quad-col x 2 consecutive rows):
//     4x ds_read_b128 + 8x ds_read_b32 per pair, 72 FMA, 2 nontemporal
//     dwordx4 stores. Vertical HBM re-read amplification 1.5x -> 1.06x.
//   - Zero-padding at plane edges done with cndmask selects (rows) and
//     hasL/hasR (cols), staging clamps source rows for address safety only.

#define BB 16
#define CC 64
#define HH 192
#define WW 192
#define KERLEN (CC * 9)       // 576 per batch
#define QW (WW / 4)           // 48 quads per row
#define ROWS 32               // output rows per tile
#define RIN (ROWS + 2)        // 34 staged rows
#define ROWB (WW * 4)         // 768 bytes per row
#define TILEB (RIN * ROWB)    // 26112 bytes actually used
#define STAGEB (7 * 4096)     // 28672 bytes staged (tail rows clamped, unread)
#define TILES (HH / ROWS)     // 6 tiles per plane

typedef float f4 __attribute__((ext_vector_type(4)));

// ---- Kernel 1: generate the 1024 per-(b,c) 3x3 kernels into d_ws ----
__global__ __launch_bounds__(256) void gen_kernels(
    const float* __restrict__ d,   // (B, C)
    const float* __restrict__ w1,  // (C, C)
    const float* __restrict__ w2,  // (C*9, C)
    float* __restrict__ ker)       // (B*C*9)
{
    __shared__ float dd[CC];
    __shared__ float hid[CC];
    const int b = blockIdx.x;
    const int t = threadIdx.x;

    if (t < CC) dd[t] = d[b * CC + t];
    __syncthreads();

    if (t < CC) {
        const float* w1r = w1 + t * CC;
        float acc = 0.f;
        #pragma unroll 8
        for (int m = 0; m < CC; ++m) acc += dd[m] * w1r[m];
        hid[t] = acc > 0.f ? acc : 0.1f * acc;
    }
    __syncthreads();

    for (int o = t; o < KERLEN; o += 256) {
        const float* w2r = w2 + o * CC;
        float acc = 0.f;
        #pragma unroll 8
        for (int k = 0; k < CC; ++k) acc += hid[k] * w2r[k];
        ker[b * KERLEN + o] = acc;
    }
}

__device__ __forceinline__ void gload_lds16(const float* g, float* l) {
    __builtin_amdgcn_global_load_lds(
        (const __attribute__((address_space(1))) unsigned int*)g,
        (__attribute__((address_space(3))) unsigned int*)l,
        16, 0, 0);
}

// ---- Kernel 2: depthwise 3x3, LDS-staged 32-row tile ----
__global__ __launch_bounds__(256, 5) void dconv3x3_v5(
    const float* __restrict__ x,    // (B*C, H, W)
    const float* __restrict__ ker,  // (B*C, 9)
    float* __restrict__ out)        // (B*C, H, W)
{
    __shared__ __align__(16) float lds[STAGEB / 4];   // 7168 floats = 28 KB

    const int blk  = blockIdx.x;
    const int bc   = blk / TILES;
    const int tile = blk - bc * TILES;
    const int r0   = tile * ROWS;                     // first output row

    const float* __restrict__ xp = x   + (size_t)bc * HH * WW;
    float* __restrict__       op = out + (size_t)bc * HH * WW;

    // block-uniform coefficients -> scalar loads (SGPRs)
    const float* kp = ker + bc * 9;
    const float k00 = kp[0], k01 = kp[1], k02 = kp[2];
    const float k10 = kp[3], k11 = kp[4], k12 = kp[5];
    const float k20 = kp[6], k21 = kp[7], k22 = kp[8];

    const int t = threadIdx.x;

    // ---- stage 34 rows (+ clamped pad rows) into LDS, 16 B per lane ----
    #pragma unroll
    for (int i = 0; i < 7; ++i) {
        const int idx  = i * 4096 + t * 16;           // byte offset in tile
        const int j    = idx / ROWB;                  // staged row 0..37
        const int colb = idx - j * ROWB;              // 16B-aligned col byte
        int srow = r0 - 1 + j;
        srow = srow < 0 ? 0 : (srow > HH - 1 ? HH - 1 : srow);
        gload_lds16(xp + srow * WW + (colb >> 2), lds + (idx >> 2));
    }
    asm volatile("s_waitcnt vmcnt(0)" ::: "memory");
    __syncthreads();

    // ---- compute: 3 tasks/thread, each = 1 quad-col x 2 output rows ----
    const f4 zero = {0.f, 0.f, 0.f, 0.f};

    #pragma unroll
    for (int k2 = 0; k2 < 3; ++k2) {
        const int task = t + k2 * 256;                // 0..767
        const int pr   = task / QW;                   // row-pair 0..15
        const int q    = task - pr * QW;              // quad col 0..47
        const int lr0  = pr * 2;                      // local out row base

        const bool hasL = (q > 0);
        const bool hasR = (q < QW - 1);
        const int  offL = hasL ? -1 : 0;
        const int  offR = hasR ?  4 : 0;

        f4    c[4];
        float l[4], r[4];

        #pragma unroll
        for (int dj = 0; dj < 4; ++dj) {
            const int g = r0 + lr0 - 1 + dj;          // global input row
            const float* p = lds + (lr0 + dj) * WW + q * 4;
            const f4 v     = *(const f4*)p;
            const float lv = p[offL];
            const float rv = p[offR];
            const bool ok  = (unsigned)g < (unsigned)HH;
            c[dj] = ok ? v : zero;
            l[dj] = (ok && hasL) ? lv : 0.f;
            r[dj] = (ok && hasR) ? rv : 0.f;
        }

        #pragma unroll
        for (int i = 0; i < 2; ++i) {
            const f4 ca = c[i], cb = c[i + 1], cd = c[i + 2];
            const float la = l[i], lb = l[i + 1], lc = l[i + 2];
            const float ra = r[i], rb = r[i + 1], rc = r[i + 2];

            f4 o;
            o.x = k00 * la   + k01 * ca.x + k02 * ca.y
                + k10 * lb   + k11 * cb.x + k12 * cb.y
                + k20 * lc   + k21 * cd.x + k22 * cd.y;
            o.y = k00 * ca.x + k01 * ca.y + k02 * ca.z
                + k10 * cb.x + k11 * cb.y + k12 * cb.z
                + k20 * cd.x + k21 * cd.y + k22 * cd.z;
            o.z = k00 * ca.y + k01 * ca.z + k02 * ca.w
                + k10 * cb.y + k11 * cb.z + k12 * cb.w
                + k20 * cd.y + k21 * cd.z + k22 * cd.w;
            o.w = k00 * ca.z + k01 * ca.w + k02 * ra
                + k10 * cb.z + k11 * cb.w + k12 * rb
                + k20 * cd.z + k21 * cd.w + k22 * rc;

            __builtin_nontemporal_store(
                o, (f4*)(op + (size_t)(r0 + lr0 + i) * WW + q * 4));
        }
    }
}

extern "C" void kernel_launch(void* const* d_in, const int* in_sizes, int n_in,
                              void* d_out, int out_size, void* d_ws, size_t ws_size,
                              hipStream_t stream) {
    const float* x0 = (const float*)d_in[0];  // (16,64,192,192)
    const float* d  = (const float*)d_in[1];  // (16,64)
    const float* w1 = (const float*)d_in[2];  // (64,64)
    const float* w2 = (const float*)d_in[3];  // (576,64)
    float* out = (float*)d_out;
    float* ker = (float*)d_ws;                // 9216 floats

    gen_kernels<<<BB, 256, 0, stream>>>(d, w1, w2, ker);
    dconv3x3_v5<<<BB * CC * TILES, 256, 0, stream>>>(x0, ker, out);
}